// Round 3
// baseline (1739.586 us; speedup 1.0000x reference)
//
#include <hip/hip_runtime.h>

#define TB 512

constexpr int BHC = 32;     // B*H
constexpr int LEN = 8192;   // L
constexpr int DD  = 64;     // d
constexpr int RR  = 266;    // num_rows
constexpr int RP  = 272;    // padded to 16*17
constexpr float EPSF = 1e-3f;

// ---------------------------------------------------------------------------
// K1: grid (8, 32), 512 thr. Block = 1024 l-rows = 8 subtiles x 128 rows.
// Per subtile: phase2 f[4][17] features (4 l/thread), then 4 quarters of
// 32 rows: kp (quad-swizzled, float4-over-l) -> phase3 outer-product.
// LDS: proj 69632 + k4 32768 + v4 16384 + kpq 34816 = 153600 B
// ---------------------------------------------------------------------------
__global__ __launch_bounds__(TB, 2) void perf_kv_kernel(
    const float* __restrict__ kin, const float* __restrict__ vin,
    const float* __restrict__ proj,
    float* __restrict__ kv_ws, float* __restrict__ ksum_ws)
{
  __shared__ __align__(16) float4 proj4[RP * 16];  // [r][c4] at r*16 + (c4^(r&15))
  __shared__ __align__(16) float4 k4[128 * 16];    // [l][c4] swizzled likewise
  __shared__ __align__(16) float4 v4[64 * 16];     // [l][c4] plain, half-staged
  __shared__ __align__(16) float4 kpq[RP * 8];     // kp^T quarter: [r][lq] at r*8+(cq^(r&7))

  const int t  = threadIdx.x;
  const int bh = blockIdx.y;
  const float* kb = kin + (size_t)bh * LEN * DD;
  const float* vb = vin + (size_t)bh * LEN * DD;
  const int l0 = blockIdx.x * 1024;

  for (int idx = t; idx < RP * 16; idx += TB) {
    int r = idx >> 4, c4 = idx & 15;
    float4 val = make_float4(0.f, 0.f, 0.f, 0.f);
    if (r < RR) val = ((const float4*)proj)[idx];
    proj4[(r << 4) + (c4 ^ (r & 15))] = val;
  }

  const int rg = t & 15;                    // phase-2: r = rg + 16i
  const int lg = t >> 4;                    // phase-2: rows 4lg..4lg+3 of subtile
  const int tr = t & 15, td = (t >> 4) & 15, ls = t >> 8;  // phase-3 map
  const int trl = tr & 7;                   // phase-3 swizzle key (r&7 == tr&7)

  float4 acc[17];
  float  ksacc[17];
#pragma unroll
  for (int i = 0; i < 17; ++i) { acc[i] = make_float4(0.f,0.f,0.f,0.f); ksacc[i] = 0.f; }

  for (int s = 0; s < 8; ++s) {
    const int ls0 = l0 + s * 128;
    // stage K (128 rows, swizzled) + V rows [0,64)
#pragma unroll
    for (int u = 0; u < 4; ++u) {
      int idx = t + u * TB;                 // 0..2047
      int rw = idx >> 4, c4 = idx & 15;
      k4[(rw << 4) + (c4 ^ (rw & 15))] = ((const float4*)(kb + (size_t)ls0 * DD))[idx];
    }
#pragma unroll
    for (int u = 0; u < 2; ++u) {
      int idx = t + u * TB;                 // 0..1023
      v4[idx] = ((const float4*)(vb + (size_t)ls0 * DD))[idx];
    }
    __syncthreads();

    // phase 2: features for 128 rows x 272 r; thread: 4 l x 17 r
    float f[4][17];
#pragma unroll
    for (int j = 0; j < 4; ++j)
#pragma unroll
      for (int i = 0; i < 17; ++i) f[j][i] = 0.f;

#pragma unroll 2
    for (int c4 = 0; c4 < 16; ++c4) {
      float4 kk[4];
#pragma unroll
      for (int j = 0; j < 4; ++j) {
        int rw = 4 * lg + j;
        kk[j] = k4[(rw << 4) + (c4 ^ (rw & 15))];
      }
      const int sx = c4 ^ rg;
#pragma unroll
      for (int i = 0; i < 17; ++i) {
        float4 p4 = proj4[((rg + (i << 4)) << 4) + sx];
#pragma unroll
        for (int j = 0; j < 4; ++j)
          f[j][i] += kk[j].x*p4.x + kk[j].y*p4.y + kk[j].z*p4.z + kk[j].w*p4.w;
      }
    }

    // 4 quarters of 32 rows
    for (int q = 0; q < 4; ++q) {
      if (q == 2) {                         // restage V rows [64,128)
#pragma unroll
        for (int u = 0; u < 2; ++u) {
          int idx = t + u * TB;
          v4[idx] = ((const float4*)(vb + (size_t)(ls0 + 64) * DD))[idx];
        }
      }
      if ((lg >> 3) == q) {                 // write kp quarter (float4 over l)
        const int cq = lg & 7;
        const int rgl = rg & 7;
#pragma unroll
        for (int i = 0; i < 17; ++i) {
          int r = rg + (i << 4);
          float4 w;
          if (r < RR) {
            w.x = fmaxf(f[0][i], 0.f) + EPSF;
            w.y = fmaxf(f[1][i], 0.f) + EPSF;
            w.z = fmaxf(f[2][i], 0.f) + EPSF;
            w.w = fmaxf(f[3][i], 0.f) + EPSF;
          } else {
            w = make_float4(0.f, 0.f, 0.f, 0.f);
          }
          kpq[r * 8 + (cq ^ rgl)] = w;
          ksacc[i] += w.x + w.y + w.z + w.w;
        }
      }
      __syncthreads();

      // phase 3 on quarter q: acc[i] += sum_l kp[l][tr+16i] * V[l][4td..]
      const int vbase = (q & 1) * 32;
#pragma unroll
      for (int cc = 0; cc < 4; ++cc) {
        const int lcol = ls * 16 + 4 * cc;  // row-in-quarter base
        const int cq = lcol >> 2;           // 0..7
        float4 vv0 = v4[((vbase + lcol + 0) << 4) + td];
        float4 vv1 = v4[((vbase + lcol + 1) << 4) + td];
        float4 vv2 = v4[((vbase + lcol + 2) << 4) + td];
        float4 vv3 = v4[((vbase + lcol + 3) << 4) + td];
        const int slot = cq ^ trl;
#pragma unroll
        for (int i = 0; i < 17; ++i) {
          int r = tr + (i << 4);
          float4 kq = kpq[r * 8 + slot];
          acc[i].x += kq.x*vv0.x + kq.y*vv1.x + kq.z*vv2.x + kq.w*vv3.x;
          acc[i].y += kq.x*vv0.y + kq.y*vv1.y + kq.z*vv2.y + kq.w*vv3.y;
          acc[i].z += kq.x*vv0.z + kq.y*vv1.z + kq.z*vv2.z + kq.w*vv3.z;
          acc[i].w += kq.x*vv0.w + kq.y*vv1.w + kq.z*vv2.w + kq.w*vv3.w;
        }
      }
      __syncthreads();
    }
  }

  float* kvb = kv_ws + (size_t)bh * RP * DD;
#pragma unroll
  for (int i = 0; i < 17; ++i) {
    int r = tr + (i << 4);
    float* p = kvb + r * DD + (td << 2);
    atomicAdd(p + 0, acc[i].x);
    atomicAdd(p + 1, acc[i].y);
    atomicAdd(p + 2, acc[i].z);
    atomicAdd(p + 3, acc[i].w);
  }
  float* ksb = ksum_ws + bh * RP;
#pragma unroll
  for (int i = 0; i < 17; ++i) atomicAdd(ksb + rg + (i << 4), ksacc[i]);
}

// ---------------------------------------------------------------------------
// K2: grid (128, 32), 512 thr, 64 rows/block. Features 2 l/thread into
// qp_t[272][66]; phase B reads qp from LDS, KV from global (L1/L2-resident),
// proj stays LDS-resident. LDS: 69632 + 16384 + 71808 + 1088 = 158912 B
// ---------------------------------------------------------------------------
__global__ __launch_bounds__(TB, 2) void perf_out_kernel(
    const float* __restrict__ qin, const float* __restrict__ proj,
    const float* __restrict__ kv_ws, const float* __restrict__ ksum_ws,
    float* __restrict__ out)
{
  __shared__ __align__(16) float4 proj4[RP * 16];  // 69632
  __shared__ __align__(16) float4 q4[64 * 16];     // 16384
  __shared__ float qp_t[RP * 66];                  // 71808  [r][lcol], stride 66
  __shared__ float ksum_lds[RP];                   // 1088

  const int t  = threadIdx.x;
  const int bh = blockIdx.y;
  const int l0 = blockIdx.x * 64;
  const float* qb = qin + (size_t)bh * LEN * DD;

  for (int idx = t; idx < RP * 16; idx += TB) {
    int r = idx >> 4, c4 = idx & 15;
    float4 val = make_float4(0.f, 0.f, 0.f, 0.f);
    if (r < RR) val = ((const float4*)proj)[idx];
    proj4[(r << 4) + (c4 ^ (r & 15))] = val;
  }
  if (t < RP) ksum_lds[t] = ksum_ws[bh * RP + t];
#pragma unroll
  for (int u = 0; u < 2; ++u) {
    int idx = t + u * TB;                   // 0..1023
    int rw = idx >> 4, c4 = idx & 15;
    q4[(rw << 4) + (c4 ^ (rw & 15))] = ((const float4*)(qb + (size_t)l0 * DD))[idx];
  }
  __syncthreads();

  // features: thread (rg, lg) -> rows 2lg,2lg+1 x r = rg+16i
  const int rg = t & 15, lg = t >> 4;
  float f[2][17];
#pragma unroll
  for (int j = 0; j < 2; ++j)
#pragma unroll
    for (int i = 0; i < 17; ++i) f[j][i] = 0.f;

#pragma unroll 2
  for (int c4 = 0; c4 < 16; ++c4) {
    int r0 = 2 * lg, r1 = 2 * lg + 1;
    float4 k0 = q4[(r0 << 4) + (c4 ^ (r0 & 15))];
    float4 k1 = q4[(r1 << 4) + (c4 ^ (r1 & 15))];
    const int sx = c4 ^ rg;
#pragma unroll
    for (int i = 0; i < 17; ++i) {
      float4 p4 = proj4[((rg + (i << 4)) << 4) + sx];
      f[0][i] += k0.x*p4.x + k0.y*p4.y + k0.z*p4.z + k0.w*p4.w;
      f[1][i] += k1.x*p4.x + k1.y*p4.y + k1.z*p4.z + k1.w*p4.w;
    }
  }
#pragma unroll
  for (int i = 0; i < 17; ++i) {
    int r = rg + (i << 4);
    float v0 = 0.f, v1 = 0.f;
    if (r < RR) {
      v0 = fmaxf(f[0][i], 0.f) + EPSF;
      v1 = fmaxf(f[1][i], 0.f) + EPSF;
    }
    *(float2*)&qp_t[r * 66 + 2 * lg] = make_float2(v0, v1);
  }
  __syncthreads();

  // phase B: thread (dq, lq) -> rows 2lq,2lq+1, d-quad dq
  const int dq = t & 15, lq = t >> 4;
  const float4* kvg = (const float4*)(kv_ws + (size_t)bh * RP * DD);
  float4 o0 = make_float4(0.f,0.f,0.f,0.f), o1 = make_float4(0.f,0.f,0.f,0.f);
  float den0 = 0.f, den1 = 0.f;
#pragma unroll 4
  for (int r = 0; r < RP; ++r) {
    float2 q2  = *(const float2*)&qp_t[r * 66 + 2 * lq];
    float4 kv4 = kvg[r * 16 + dq];
    float  ks  = ksum_lds[r];
    o0.x += q2.x*kv4.x; o0.y += q2.x*kv4.y; o0.z += q2.x*kv4.z; o0.w += q2.x*kv4.w;
    o1.x += q2.y*kv4.x; o1.y += q2.y*kv4.y; o1.z += q2.y*kv4.z; o1.w += q2.y*kv4.w;
    den0 += q2.x*ks;    den1 += q2.y*ks;
  }
  float inv0 = 1.f / den0, inv1 = 1.f / den1;
  o0.x *= inv0; o0.y *= inv0; o0.z *= inv0; o0.w *= inv0;
  o1.x *= inv1; o1.y *= inv1; o1.z *= inv1; o1.w *= inv1;
  size_t ob = ((size_t)bh * LEN + l0 + 2 * lq) * DD + (dq << 2);
  *(float4*)(out + ob)      = o0;
  *(float4*)(out + ob + DD) = o1;
}

extern "C" void kernel_launch(void* const* d_in, const int* in_sizes, int n_in,
                              void* d_out, int out_size, void* d_ws, size_t ws_size,
                              hipStream_t stream) {
  (void)in_sizes; (void)n_in; (void)out_size; (void)ws_size;
  const float* q    = (const float*)d_in[0];
  const float* k    = (const float*)d_in[1];
  const float* v    = (const float*)d_in[2];
  const float* proj = (const float*)d_in[3];
  float* out     = (float*)d_out;
  float* kv_ws   = (float*)d_ws;                       // [32][272][64]
  float* ksum_ws = kv_ws + (size_t)BHC * RP * DD;      // [32][272]

  size_t zbytes = ((size_t)BHC * RP * DD + (size_t)BHC * RP) * sizeof(float);
  hipMemsetAsync(d_ws, 0, zbytes, stream);             // ws re-poisoned each launch

  perf_kv_kernel<<<dim3(8, BHC), dim3(TB), 0, stream>>>(k, v, proj, kv_ws, ksum_ws);
  perf_out_kernel<<<dim3(LEN / 64, BHC), dim3(TB), 0, stream>>>(q, proj, kv_ws, ksum_ws, out);
}

// Round 4
// 450.647 us; speedup vs baseline: 3.8602x; 3.8602x over previous
//
#include <hip/hip_runtime.h>

typedef __attribute__((ext_vector_type(8))) short short8;
typedef __attribute__((ext_vector_type(4))) float f32x4;

#define MFMA16(a,b,c) __builtin_amdgcn_mfma_f32_16x16x32_bf16((a),(b),(c),0,0,0)

constexpr int BHC = 32;     // B*H
constexpr int LEN = 8192;   // L
constexpr int DD  = 64;     // d
constexpr int RR  = 266;    // num_rows
constexpr int RP  = 272;    // 17*16
constexpr float EPSF = 1e-3f;

__device__ __forceinline__ unsigned short f2bf(float x) {   // RNE f32->bf16 bits
  unsigned u = __builtin_bit_cast(unsigned, x);
  return (unsigned short)((u + 0x7FFFu + ((u >> 16) & 1u)) >> 16);
}
__device__ __forceinline__ float bf2f(unsigned short h) {
  return __builtin_bit_cast(float, (unsigned)h << 16);
}
__device__ __forceinline__ void split2(float x, unsigned short& h, unsigned short& l) {
  h = f2bf(x);
  l = f2bf(x - bf2f(h));
}

// ---------------------------------------------------------------------------
// K1: per (bh, 1024-row chunk), 32 subtiles of 32 rows.
//   MFMA1: feat = relu(K@P^T)+eps  (A=K-frag from LDS, B=P-frag in regs)
//   MFMA2: KV^T[dd][r] += V^T @ feat (A=V^T built from V_lds, B=fT from LDS)
//   ksum[r] += feat col-sums. atomicAdd into ws.
// LDS: K 2x9216 + V_lds 8704 + fT 2x21760 = 61440 B (1 blk/CU, 8 waves)
// ---------------------------------------------------------------------------
__global__ __launch_bounds__(512, 1) void perf_kv_kernel(
    const float* __restrict__ kin, const float* __restrict__ vin,
    const float* __restrict__ proj,
    float* __restrict__ kv_ws, float* __restrict__ ksum_ws)
{
  __shared__ unsigned short K_hi[32*72], K_lo[32*72];   // [l][d] pad 72 (2-way banks)
  __shared__ float V_lds[32*68];                        // [l][d] f32, pad 68
  __shared__ unsigned int fT_hi[RP*20], fT_lo[RP*20];   // [r][l-pair u32], pad 20

  const int t = threadIdx.x;
  const int wid = t >> 6, lane = t & 63, g = lane >> 4, ln = lane & 15;
  const int bh = blockIdx.y;
  const float* kb = kin + (size_t)bh * LEN * DD + (size_t)blockIdx.x * 1024 * DD;
  const float* vb = vin + (size_t)bh * LEN * DD + (size_t)blockIdx.x * 1024 * DD;

  // --- P-fragments in registers: wave's MFMA1 r-tiles {2w, 2w+1, [w7] 16} ---
  const int nrt1 = (wid == 7) ? 3 : 2;
  short8 Ph[3][2], Pl[3][2];
#pragma unroll
  for (int j = 0; j < 3; ++j) {
    const int rt = (j == 2) ? 16 : 2 * wid + j;
#pragma unroll
    for (int c = 0; c < 2; ++c) {
      const int r = rt * 16 + ln;
      float pv[8];
      if (j < nrt1 && r < RR) {
        const float4 a = *(const float4*)&proj[r * DD + c * 32 + g * 8];
        const float4 b = *(const float4*)&proj[r * DD + c * 32 + g * 8 + 4];
        pv[0]=a.x; pv[1]=a.y; pv[2]=a.z; pv[3]=a.w;
        pv[4]=b.x; pv[5]=b.y; pv[6]=b.z; pv[7]=b.w;
      } else {
#pragma unroll
        for (int i = 0; i < 8; ++i) pv[i] = 0.f;
      }
#pragma unroll
      for (int i = 0; i < 8; ++i) {
        unsigned short h, l; split2(pv[i], h, l);
        Ph[j][c][i] = (short)h; Pl[j][c][i] = (short)l;
      }
    }
  }

  f32x4 kvacc[9];
#pragma unroll
  for (int j = 0; j < 9; ++j) kvacc[j] = (f32x4){0.f,0.f,0.f,0.f};
  float ksacc[3] = {0.f, 0.f, 0.f};

  const int dt = wid & 3;                 // MFMA2 dd-tile
  const int rbase2 = (wid >> 2) * 9;      // MFMA2 r-tiles: 0..8 / 9..16
  const int nrt2 = (wid >> 2) ? 8 : 9;

  for (int s = 0; s < 32; ++s) {
    { // ---- stage K (bf16 hi/lo) + V (f32) ----
      const int l = t >> 4, c4 = t & 15;
      const float4 kv4 = *(const float4*)&kb[(size_t)(s*32 + l) * DD + c4*4];
      const float4 vv4 = *(const float4*)&vb[(size_t)(s*32 + l) * DD + c4*4];
      unsigned short h0,q0,h1,q1,h2,q2,h3,q3;
      split2(kv4.x,h0,q0); split2(kv4.y,h1,q1); split2(kv4.z,h2,q2); split2(kv4.w,h3,q3);
      *(ushort4*)&K_hi[l*72 + c4*4] = make_ushort4(h0,h1,h2,h3);
      *(ushort4*)&K_lo[l*72 + c4*4] = make_ushort4(q0,q1,q2,q3);
      *(float4*)&V_lds[l*68 + c4*4] = vv4;
    }
    __syncthreads();

    // ---- MFMA1: feat -> fT (transposed, u32-packed l-pairs) ----
    short8 KAh[2][2], KAl[2][2];
#pragma unroll
    for (int lt = 0; lt < 2; ++lt)
#pragma unroll
    for (int c = 0; c < 2; ++c) {
      KAh[lt][c] = *(const short8*)&K_hi[(lt*16+ln)*72 + c*32 + g*8];
      KAl[lt][c] = *(const short8*)&K_lo[(lt*16+ln)*72 + c*32 + g*8];
    }
#pragma unroll
    for (int j = 0; j < 3; ++j) if (j < nrt1) {
      const int rt = (j == 2) ? 16 : 2*wid + j;
      const int r = rt*16 + ln;
      const bool rok = r < RR;
#pragma unroll
      for (int lt = 0; lt < 2; ++lt) {
        f32x4 acc = {0.f,0.f,0.f,0.f};
#pragma unroll
        for (int c = 0; c < 2; ++c) {
          acc = MFMA16(KAh[lt][c], Ph[j][c], acc);
          acc = MFMA16(KAh[lt][c], Pl[j][c], acc);
          acc = MFMA16(KAl[lt][c], Ph[j][c], acc);
        }
        unsigned short h[4], q[4];
        float sum = 0.f;
#pragma unroll
        for (int reg = 0; reg < 4; ++reg) {
          const float fv = rok ? (fmaxf(acc[reg], 0.f) + EPSF) : 0.f;
          sum += fv;
          split2(fv, h[reg], q[reg]);
        }
        ksacc[j] += sum;
        *(uint2*)&fT_hi[r*20 + lt*8 + g*2] =
            make_uint2((unsigned)h[0] | ((unsigned)h[1]<<16),
                       (unsigned)h[2] | ((unsigned)h[3]<<16));
        *(uint2*)&fT_lo[r*20 + lt*8 + g*2] =
            make_uint2((unsigned)q[0] | ((unsigned)q[1]<<16),
                       (unsigned)q[2] | ((unsigned)q[3]<<16));
      }
    }
    __syncthreads();

    // ---- MFMA2: KV^T += V^T x feat over this subtile's 32 l ----
    short8 VAh, VAl;
#pragma unroll
    for (int i = 0; i < 8; ++i) {
      const float v = V_lds[(g*8 + i)*68 + dt*16 + ln];
      unsigned short h, l; split2(v, h, l);
      VAh[i] = (short)h; VAl[i] = (short)l;
    }
#pragma unroll
    for (int j = 0; j < 9; ++j) if (j < nrt2) {
      const int rt = rbase2 + j;
      const short8 Bh = *(const short8*)&fT_hi[(rt*16+ln)*20 + g*4];
      const short8 Bl = *(const short8*)&fT_lo[(rt*16+ln)*20 + g*4];
      f32x4 a = kvacc[j];
      a = MFMA16(VAh, Bh, a);
      a = MFMA16(VAh, Bl, a);
      a = MFMA16(VAl, Bh, a);
      kvacc[j] = a;
    }
    __syncthreads();
  }

  // ---- epilogue: merge partials ----
  float* kvb = kv_ws + (size_t)bh * DD * RP;
#pragma unroll
  for (int j = 0; j < 9; ++j) if (j < nrt2) {
    const int rt = rbase2 + j;
#pragma unroll
    for (int reg = 0; reg < 4; ++reg)
      atomicAdd(&kvb[(dt*16 + g*4 + reg) * RP + rt*16 + ln], kvacc[j][reg]);
  }
#pragma unroll
  for (int j = 0; j < 3; ++j) if (j < nrt1) {
    const int rt = (j == 2) ? 16 : 2*wid + j;
    float v = ksacc[j];
    v += __shfl_xor(v, 16);
    v += __shfl_xor(v, 32);
    if (lane < 16) atomicAdd(&ksum_ws[bh * RP + rt*16 + lane], v);
  }
}

// ---------------------------------------------------------------------------
// K2: per (bh, 1024-row chunk), 32 subtiles of 32 rows.
//   MFMA1': feat_Q^T tiles (A=P from LDS, B=Q from LDS), written row-major
//           b64-packed; den[l] accumulated via LDS atomics in the same phase.
//   GEMM4:  out = (feat_Q @ KV) / den  (A=feat from LDS, B=KV^T in regs)
// LDS: P 78336 + feat 2x18944 + Q 2x4608 + ksum 1088 + den 128 = 126656 B
// ---------------------------------------------------------------------------
__global__ __launch_bounds__(512, 1) void perf_out_kernel(
    const float* __restrict__ qin, const float* __restrict__ proj,
    const float* __restrict__ kv_ws, const float* __restrict__ ksum_ws,
    float* __restrict__ out)
{
  __shared__ unsigned short P_hi[RP*72], P_lo[RP*72];     // [r][d] pad 72
  __shared__ unsigned short feat_hi[32*296], feat_lo[32*296]; // [l][r] pad 296
  __shared__ unsigned short Q_hi[32*72], Q_lo[32*72];
  __shared__ float ksum_lds[RP];
  __shared__ float den_l[32];

  const int t = threadIdx.x;
  const int wid = t >> 6, lane = t & 63, g = lane >> 4, ln = lane & 15;
  const int bh = blockIdx.y;
  const float* qb = qin + (size_t)bh * LEN * DD + (size_t)blockIdx.x * 1024 * DD;
  float* ob = out + (size_t)bh * LEN * DD + (size_t)blockIdx.x * 1024 * DD;

  // ---- block-start staging ----
  for (int idx = t; idx < RP * 16; idx += 512) {          // P -> LDS bf16 hi/lo
    const int row = idx >> 4, c4 = idx & 15;
    float4 val = make_float4(0.f, 0.f, 0.f, 0.f);
    if (row < RR) val = *(const float4*)&proj[row * DD + c4 * 4];
    unsigned short h0,q0,h1,q1,h2,q2,h3,q3;
    split2(val.x,h0,q0); split2(val.y,h1,q1); split2(val.z,h2,q2); split2(val.w,h3,q3);
    *(ushort4*)&P_hi[row*72 + c4*4] = make_ushort4(h0,h1,h2,h3);
    *(ushort4*)&P_lo[row*72 + c4*4] = make_ushort4(q0,q1,q2,q3);
  }
  for (int idx = t; idx < 32 * 32; idx += 512) {          // zero feat pad cols
    const int row = idx >> 5, c = 272 + (idx & 31);
    if (c < 296) { feat_hi[row*296 + c] = 0; feat_lo[row*296 + c] = 0; }
  }
  if (t < RP) ksum_lds[t] = ksum_ws[bh*RP + t];

  // KV^T fragments in registers: wave's dd-tile = wid&3 (x2 duplication)
  const int dt = wid & 3;
  short8 KVh[9], KVl[9];
  {
    const float* kvr = kv_ws + ((size_t)bh*DD + dt*16 + ln) * RP;
#pragma unroll
    for (int kc = 0; kc < 9; ++kc) {
      const int r0 = kc*32 + g*8;
      float pv[8];
      if (r0 + 7 < RP) {
        const float4 a = *(const float4*)&kvr[r0];
        const float4 b = *(const float4*)&kvr[r0 + 4];
        pv[0]=a.x; pv[1]=a.y; pv[2]=a.z; pv[3]=a.w;
        pv[4]=b.x; pv[5]=b.y; pv[6]=b.z; pv[7]=b.w;
      } else {
#pragma unroll
        for (int i = 0; i < 8; ++i) pv[i] = 0.f;
      }
#pragma unroll
      for (int i = 0; i < 8; ++i) {
        unsigned short h, l; split2(pv[i], h, l);
        KVh[kc][i] = (short)h; KVl[kc][i] = (short)l;
      }
    }
  }

  const int nrt1 = (wid >= 6) ? 3 : 2;    // MFMA1' r-tiles {2w,2w+1,[w6/7 split]16}
  const int lt4 = wid >> 2, dt4 = wid & 3; // GEMM4 tile

  __syncthreads();

  for (int s = 0; s < 32; ++s) {
    { // ---- stage Q + zero den ----
      const int l = t >> 4, c4 = t & 15;
      const float4 qv4 = *(const float4*)&qb[(size_t)(s*32 + l) * DD + c4*4];
      unsigned short h0,q0,h1,q1,h2,q2,h3,q3;
      split2(qv4.x,h0,q0); split2(qv4.y,h1,q1); split2(qv4.z,h2,q2); split2(qv4.w,h3,q3);
      *(ushort4*)&Q_hi[l*72 + c4*4] = make_ushort4(h0,h1,h2,h3);
      *(ushort4*)&Q_lo[l*72 + c4*4] = make_ushort4(q0,q1,q2,q3);
      if (t < 32) den_l[t] = 0.f;
    }
    __syncthreads();

    // ---- MFMA1': feat_Q^T tiles; den via LDS atomics ----
#pragma unroll
    for (int j = 0; j < 3; ++j) if (j < nrt1) {
      const int rt = (j == 2) ? 16 : 2*wid + j;
      short8 PAh[2], PAl[2];
#pragma unroll
      for (int c = 0; c < 2; ++c) {
        PAh[c] = *(const short8*)&P_hi[(rt*16+ln)*72 + c*32 + g*8];
        PAl[c] = *(const short8*)&P_lo[(rt*16+ln)*72 + c*32 + g*8];
      }
#pragma unroll
      for (int lt = 0; lt < 2; ++lt) {
        if (j == 2 && lt != (wid & 1)) continue;   // w6: lt0, w7: lt1
        f32x4 acc = {0.f,0.f,0.f,0.f};
#pragma unroll
        for (int c = 0; c < 2; ++c) {
          const short8 QBh = *(const short8*)&Q_hi[(lt*16+ln)*72 + c*32 + g*8];
          const short8 QBl = *(const short8*)&Q_lo[(lt*16+ln)*72 + c*32 + g*8];
          acc = MFMA16(PAh[c], QBh, acc);
          acc = MFMA16(PAh[c], QBl, acc);
          acc = MFMA16(PAl[c], QBh, acc);
        }
        // C[m=r][n=l]: lane holds r = rt*16+g*4+reg, l = lt*16+ln
        unsigned short h[4], q[4];
        float dacc = 0.f;
#pragma unroll
        for (int reg = 0; reg < 4; ++reg) {
          const int r = rt*16 + g*4 + reg;
          const float fv = (r < RR) ? (fmaxf(acc[reg], 0.f) + EPSF) : 0.f;
          dacc += fv * ksum_lds[r];
          split2(fv, h[reg], q[reg]);
        }
        atomicAdd(&den_l[lt*16 + ln], dacc);
        *(ushort4*)&feat_hi[(lt*16+ln)*296 + rt*16 + g*4] = make_ushort4(h[0],h[1],h[2],h[3]);
        *(ushort4*)&feat_lo[(lt*16+ln)*296 + rt*16 + g*4] = make_ushort4(q[0],q[1],q[2],q[3]);
      }
    }
    __syncthreads();

    // ---- GEMM4: out-tile (lt4, dt4), k over 288 r ----
    f32x4 oacc = {0.f,0.f,0.f,0.f};
#pragma unroll
    for (int kc = 0; kc < 9; ++kc) {
      const short8 Ah = *(const short8*)&feat_hi[(lt4*16+ln)*296 + kc*32 + g*8];
      const short8 Al = *(const short8*)&feat_lo[(lt4*16+ln)*296 + kc*32 + g*8];
      oacc = MFMA16(Ah, KVh[kc], oacc);
      oacc = MFMA16(Ah, KVl[kc], oacc);
      oacc = MFMA16(Al, KVh[kc], oacc);
    }
#pragma unroll
    for (int reg = 0; reg < 4; ++reg) {
      const int l = lt4*16 + g*4 + reg;
      ob[(size_t)(s*32 + l) * DD + dt4*16 + ln] = oacc[reg] / den_l[l];
    }
    __syncthreads();
  }
}

extern "C" void kernel_launch(void* const* d_in, const int* in_sizes, int n_in,
                              void* d_out, int out_size, void* d_ws, size_t ws_size,
                              hipStream_t stream) {
  (void)in_sizes; (void)n_in; (void)out_size; (void)ws_size;
  const float* q    = (const float*)d_in[0];
  const float* k    = (const float*)d_in[1];
  const float* v    = (const float*)d_in[2];
  const float* proj = (const float*)d_in[3];
  float* out     = (float*)d_out;
  float* kv_ws   = (float*)d_ws;                       // [32][64][272] = KV^T
  float* ksum_ws = kv_ws + (size_t)BHC * DD * RP;      // [32][272]

  size_t zbytes = ((size_t)BHC * DD * RP + (size_t)BHC * RP) * sizeof(float);
  hipMemsetAsync(d_ws, 0, zbytes, stream);

  perf_kv_kernel<<<dim3(8, BHC), dim3(512), 0, stream>>>(k, v, proj, kv_ws, ksum_ws);
  perf_out_kernel<<<dim3(8, BHC), dim3(512), 0, stream>>>(q, proj, kv_ws, ksum_ws, out);
}